// Round 4
// baseline (199.490 us; speedup 1.0000x reference)
//
#include <hip/hip_runtime.h>

typedef int   v4i __attribute__((ext_vector_type(4)));
typedef float v4f __attribute__((ext_vector_type(4)));

// Precompute per-face interpolatable vertex scores: fc[f] = (v0, v1, v2, 0)
__global__ void face_attr_kernel(const float* __restrict__ verts,
                                 const int* __restrict__ faces,
                                 v4f* __restrict__ fc, int F) {
    int f = blockIdx.x * blockDim.x + threadIdx.x;
    if (f < F) {
        int i0 = faces[f * 3 + 0];
        int i1 = faces[f * 3 + 1];
        int i2 = faces[f * 3 + 2];
        v4f v = {verts[i0], verts[i1], verts[i2], 0.0f};
        fc[f] = v;
    }
}

// 8 pixels (16 K-slots) per thread. All loads issued before any use:
//   p2f:  4x v4i nontemporal (single-use streaming)
//   bary: 12x v4f nontemporal
//   fc:   16x v4f clamped gathers (cached; table is L2-resident)
//   out:  4x v4i nontemporal stores
#define BF(j) b[(j) >> 2][(j) & 3]
__global__ void __launch_bounds__(256)
seg_kernel(const int* __restrict__ p2f,
           const float* __restrict__ bary,
           const v4f* __restrict__ fc,
           int* __restrict__ out, long nPix) {
    long t = (long)blockIdx.x * blockDim.x + threadIdx.x;
    long base = t * 8;                       // first pixel of this thread

    if (base + 8 <= nPix) {
        const v4i* p4 = (const v4i*)(p2f + base * 2);
        const v4f* b4 = (const v4f*)(bary + base * 6);

        v4i p[4];
        #pragma unroll
        for (int j = 0; j < 4; ++j) p[j] = __builtin_nontemporal_load(&p4[j]);

        v4f b[12];
        #pragma unroll
        for (int j = 0; j < 12; ++j) b[j] = __builtin_nontemporal_load(&b4[j]);

        // Issue all 16 gathers (clamp negative to 0; mask later).
        v4f f[16];
        #pragma unroll
        for (int s = 0; s < 16; ++s) f[s] = fc[max(p[s >> 2][s & 3], 0)];

        int r[16];
        #pragma unroll
        for (int i = 0; i < 8; ++i) {
            int s0 = 2 * i, s1 = 2 * i + 1;
            int i0 = p[s0 >> 2][s0 & 3];
            int i1 = p[s1 >> 2][s1 & 3];
            r[s0] = i0 < 0 ? 0 : (int)(BF(6 * i + 0) * f[s0][0] +
                                       BF(6 * i + 1) * f[s0][1] +
                                       BF(6 * i + 2) * f[s0][2]);
            r[s1] = i1 < 0 ? 0 : (int)(BF(6 * i + 3) * f[s1][0] +
                                       BF(6 * i + 4) * f[s1][1] +
                                       BF(6 * i + 5) * f[s1][2]);
        }

        v4i* o4 = (v4i*)(out + base * 2);
        #pragma unroll
        for (int j = 0; j < 4; ++j) {
            v4i rv = {r[4 * j + 0], r[4 * j + 1], r[4 * j + 2], r[4 * j + 3]};
            __builtin_nontemporal_store(rv, &o4[j]);
        }
    } else if (base < nPix) {
        // scalar tail
        for (long px = base; px < nPix; ++px) {
            int p0 = p2f[px * 2 + 0];
            int p1 = p2f[px * 2 + 1];
            const float* bb = bary + px * 6;
            int r0 = 0, r1 = 0;
            if (p0 >= 0) {
                v4f f = fc[p0];
                r0 = (int)(bb[0] * f[0] + bb[1] * f[1] + bb[2] * f[2]);
            }
            if (p1 >= 0) {
                v4f f = fc[p1];
                r1 = (int)(bb[3] * f[0] + bb[4] * f[1] + bb[5] * f[2]);
            }
            out[px * 2 + 0] = r0;
            out[px * 2 + 1] = r1;
        }
    }
}

extern "C" void kernel_launch(void* const* d_in, const int* in_sizes, int n_in,
                              void* d_out, int out_size, void* d_ws, size_t ws_size,
                              hipStream_t stream) {
    const float* verts = (const float*)d_in[0];   // [N*V*D] f32, D=1
    const int*   faces = (const int*)d_in[1];     // [F,3] i32
    const int*   p2f   = (const int*)d_in[2];     // [N,H,W,K] i32
    const float* bary  = (const float*)d_in[3];   // [N,H,W,K,3] f32

    int  F    = in_sizes[1] / 3;
    long nPix = (long)in_sizes[2] / 2;            // K = 2
    int* out  = (int*)d_out;

    const int BLK = 256;

    face_attr_kernel<<<(F + BLK - 1) / BLK, BLK, 0, stream>>>(
        verts, faces, (v4f*)d_ws, F);

    long nThreads = (nPix + 7) / 8;
    int  grid     = (int)((nThreads + BLK - 1) / BLK);
    seg_kernel<<<grid, BLK, 0, stream>>>(
        p2f, bary, (const v4f*)d_ws, out, nPix);
}

// Round 5
// 124.594 us; speedup vs baseline: 1.6011x; 1.6011x over previous
//
#include <hip/hip_runtime.h>

typedef int   v4i __attribute__((ext_vector_type(4)));
typedef float v4f __attribute__((ext_vector_type(4)));

// Precompute per-face interpolatable vertex scores: fc[f] = (v0, v1, v2, 0)
__global__ void face_attr_kernel(const float* __restrict__ verts,
                                 const int* __restrict__ faces,
                                 v4f* __restrict__ fc, int F) {
    int f = blockIdx.x * blockDim.x + threadIdx.x;
    if (f < F) {
        int i0 = faces[f * 3 + 0];
        int i1 = faces[f * 3 + 1];
        int i2 = faces[f * 3 + 2];
        v4f v = {verts[i0], verts[i1], verts[i2], 0.0f};
        fc[f] = v;
    }
}

// Block tile: 1024 pixels = 512 pixel-pairs. Thread owns pairs {tid, tid+256}.
//   p2f:  v4i at pair*16B  -> fully coalesced (2 loads/thread)
//   bary: 24 KB/block staged global->LDS via global_load_lds (coalesced),
//         read back as 3x v4f per pair (48B, 4-way LDS conflict: benign)
//   fc:   8 random 16B gathers/thread, issued BEFORE the barrier so they
//         overlap the staging drain
//   out:  v4i at pair*16B  -> fully coalesced
#define TILE_PX    1024
#define TILE_PAIRS 512
#define BARY_LDS   (TILE_PX * 24)   // 24576 B

__global__ void __launch_bounds__(256)
seg_kernel(const int* __restrict__ p2f,
           const float* __restrict__ bary,
           const v4f* __restrict__ fc,
           int* __restrict__ out, long nPix) {
    __shared__ char lds[BARY_LDS];
    const int  tid  = threadIdx.x;
    const long tile = (long)blockIdx.x * TILE_PX;

    if (tile + TILE_PX <= nPix) {
        // ---- stage bary tile into LDS, coalesced, async (no VGPR round-trip)
        {
            const int wave = tid >> 6;
            const int lane = tid & 63;
            const char* gsrc = (const char*)bary + tile * 24 + wave * 6144 + (long)lane * 16;
            char*       ldst = lds + wave * 6144;              // wave-uniform base
            #pragma unroll
            for (int j = 0; j < 6; ++j) {
                __builtin_amdgcn_global_load_lds(
                    (const __attribute__((address_space(1))) unsigned int*)(gsrc + j * 1024),
                    (__attribute__((address_space(3))) unsigned int*)(ldst + j * 1024),
                    16, 0, 0);
            }
        }

        // ---- p2f (coalesced) + 8 independent gathers, before the barrier
        const v4i* pp = (const v4i*)(p2f + tile * 2);
        v4i pA = pp[tid];
        v4i pB = pp[tid + 256];

        v4f fA0 = fc[max(pA.x, 0)];
        v4f fA1 = fc[max(pA.y, 0)];
        v4f fA2 = fc[max(pA.z, 0)];
        v4f fA3 = fc[max(pA.w, 0)];
        v4f fB0 = fc[max(pB.x, 0)];
        v4f fB1 = fc[max(pB.y, 0)];
        v4f fB2 = fc[max(pB.z, 0)];
        v4f fB3 = fc[max(pB.w, 0)];

        __syncthreads();   // drains staging (and gathers) -- gathers needed next anyway

        // ---- bary from LDS: pair q occupies bytes [q*48, q*48+48)
        const v4f* lb = (const v4f*)lds;
        v4f a0 = lb[tid * 3 + 0];
        v4f a1 = lb[tid * 3 + 1];
        v4f a2 = lb[tid * 3 + 2];
        v4f c0 = lb[(tid + 256) * 3 + 0];
        v4f c1 = lb[(tid + 256) * 3 + 1];
        v4f c2 = lb[(tid + 256) * 3 + 2];

        v4i rA, rB;
        rA.x = pA.x < 0 ? 0 : (int)(a0.x * fA0.x + a0.y * fA0.y + a0.z * fA0.z);
        rA.y = pA.y < 0 ? 0 : (int)(a0.w * fA1.x + a1.x * fA1.y + a1.y * fA1.z);
        rA.z = pA.z < 0 ? 0 : (int)(a1.z * fA2.x + a1.w * fA2.y + a2.x * fA2.z);
        rA.w = pA.w < 0 ? 0 : (int)(a2.y * fA3.x + a2.z * fA3.y + a2.w * fA3.z);
        rB.x = pB.x < 0 ? 0 : (int)(c0.x * fB0.x + c0.y * fB0.y + c0.z * fB0.z);
        rB.y = pB.y < 0 ? 0 : (int)(c0.w * fB1.x + c1.x * fB1.y + c1.y * fB1.z);
        rB.z = pB.z < 0 ? 0 : (int)(c1.z * fB2.x + c1.w * fB2.y + c2.x * fB2.z);
        rB.w = pB.w < 0 ? 0 : (int)(c2.y * fB3.x + c2.z * fB3.y + c2.w * fB3.z);

        v4i* o = (v4i*)(out + tile * 2);
        o[tid]       = rA;
        o[tid + 256] = rB;
    } else {
        // scalar tail (unused for 1024x1024x8x2, kept for safety)
        for (long px = tile + tid; px < nPix; px += 256) {
            int p0 = p2f[px * 2 + 0];
            int p1 = p2f[px * 2 + 1];
            const float* bb = bary + px * 6;
            int r0 = 0, r1 = 0;
            if (p0 >= 0) {
                v4f f = fc[p0];
                r0 = (int)(bb[0] * f.x + bb[1] * f.y + bb[2] * f.z);
            }
            if (p1 >= 0) {
                v4f f = fc[p1];
                r1 = (int)(bb[3] * f.x + bb[4] * f.y + bb[5] * f.z);
            }
            out[px * 2 + 0] = r0;
            out[px * 2 + 1] = r1;
        }
    }
}

extern "C" void kernel_launch(void* const* d_in, const int* in_sizes, int n_in,
                              void* d_out, int out_size, void* d_ws, size_t ws_size,
                              hipStream_t stream) {
    const float* verts = (const float*)d_in[0];   // [N*V*D] f32, D=1
    const int*   faces = (const int*)d_in[1];     // [F,3] i32
    const int*   p2f   = (const int*)d_in[2];     // [N,H,W,K] i32
    const float* bary  = (const float*)d_in[3];   // [N,H,W,K,3] f32

    int  F    = in_sizes[1] / 3;
    long nPix = (long)in_sizes[2] / 2;            // K = 2
    int* out  = (int*)d_out;

    const int BLK = 256;

    face_attr_kernel<<<(F + BLK - 1) / BLK, BLK, 0, stream>>>(
        verts, faces, (v4f*)d_ws, F);

    long grid = (nPix + TILE_PX - 1) / TILE_PX;
    seg_kernel<<<(int)grid, BLK, 0, stream>>>(
        p2f, bary, (const v4f*)d_ws, out, nPix);
}